// Round 12
// baseline (652.678 us; speedup 1.0000x reference)
//
#include <hip/hip_runtime.h>

#define NU 100000
#define NI 50000
#define DD 64
#define ALPHA_C 1.0f
#define EPS_CLAMP 1e-6f

typedef _Float16 h4 __attribute__((ext_vector_type(4)));

__device__ __forceinline__ float rsum16(float v) {
  v += __shfl_xor(v, 1, 64);
  v += __shfl_xor(v, 2, 64);
  v += __shfl_xor(v, 4, 64);
  v += __shfl_xor(v, 8, 64);
  return v;
}
__device__ __forceinline__ float xgrp2(float v) {
  v += __shfl_xor(v, 16, 64);
  v += __shfl_xor(v, 32, 64);
  return v;
}
__device__ __forceinline__ float wsum(float v) { return xgrp2(rsum16(v)); }

// --- K1: fused {norms + item sums + fp16 tables | degree counts + ranks} -------
// blocks [0,GN): norm path; [GN,G): count path.
#define GN_NORM 1024
__global__ void k_norm_count(const float* __restrict__ x, float* __restrict__ inv_norm,
                             float* __restrict__ nrm, h4* __restrict__ xnih,
                             h4* __restrict__ vuh,
                             float* __restrict__ sum_xi, float* __restrict__ sum_vi,
                             const int* __restrict__ u, const int* __restrict__ it,
                             int* __restrict__ du, int* __restrict__ di,
                             unsigned short* __restrict__ ru_, unsigned short* __restrict__ ri_,
                             int E) {
  if ((int)blockIdx.x >= GN_NORM) {
    // ---- count path ----
    int bloc = (int)blockIdx.x - GN_NORM;
    int nb = (int)gridDim.x - GN_NORM;
    int t = bloc * blockDim.x + threadIdx.x;
    int stride = nb * blockDim.x;
    for (int e = t; e < E; e += stride) {
      int uu = __builtin_nontemporal_load(&u[e]);
      int ii = __builtin_nontemporal_load(&it[e]);
      ru_[e] = (unsigned short)atomicAdd(&du[uu], 1);
      ri_[e] = (unsigned short)atomicAdd(&di[ii], 1);
    }
    return;
  }
  __shared__ float sx_s[DD], sv_s[DD];
  if (threadIdx.x < DD) { sx_s[threadIdx.x] = 0.f; sv_s[threadIdx.x] = 0.f; }
  __syncthreads();
  int lane = threadIdx.x & 63;
  int g = lane >> 4, c = lane & 15;
  int wid = blockIdx.x * 4 + (threadIdx.x >> 6);
  int nw  = GN_NORM * 4;
  float sx0=0,sx1=0,sx2=0,sx3=0, sv0=0,sv1=0,sv2=0,sv3=0;
  for (int rb = wid * 4; rb < NU + NI; rb += nw * 4) {
    int r = rb + g;
    const float4 v4 = *(const float4*)(x + (size_t)r * DD + 4 * c);
    float p = v4.x*v4.x + v4.y*v4.y + v4.z*v4.z + v4.w*v4.w;
    p = rsum16(p);
    float nc  = fmaxf(sqrtf(p), 1e-12f);
    float inv = 1.0f / nc;
    if (c == 0) inv_norm[r] = inv;
    if (r >= NU) {
      int j = r - NU;
      if (c == 0) nrm[j] = nc;
      float xn0 = v4.x*inv, xn1 = v4.y*inv, xn2 = v4.z*inv, xn3 = v4.w*inv;
      h4 hw = { (_Float16)xn0, (_Float16)xn1, (_Float16)xn2, (_Float16)xn3 };
      xnih[(size_t)j * 16 + c] = hw;
      sv0 += v4.x; sv1 += v4.y; sv2 += v4.z; sv3 += v4.w;
      sx0 += xn0;  sx1 += xn1;  sx2 += xn2;  sx3 += xn3;
    } else {
      h4 hw = { (_Float16)v4.x, (_Float16)v4.y, (_Float16)v4.z, (_Float16)v4.w };
      vuh[(size_t)r * 16 + c] = hw;
    }
  }
  atomicAdd(&sx_s[4*c+0], sx0); atomicAdd(&sx_s[4*c+1], sx1);
  atomicAdd(&sx_s[4*c+2], sx2); atomicAdd(&sx_s[4*c+3], sx3);
  atomicAdd(&sv_s[4*c+0], sv0); atomicAdd(&sv_s[4*c+1], sv1);
  atomicAdd(&sv_s[4*c+2], sv2); atomicAdd(&sv_s[4*c+3], sv3);
  __syncthreads();
  if (threadIdx.x < DD) {
    atomicAdd(&sum_xi[threadIdx.x], sx_s[threadIdx.x]);
    atomicAdd(&sum_vi[threadIdx.x], sv_s[threadIdx.x]);
  }
}

// --- K3: two single-block exclusive scans --------------------------------------
__global__ void k_scan2(const int* __restrict__ cnt0, int n0, int* __restrict__ off0,
                        const int* __restrict__ cnt1, int n1, int* __restrict__ off1) {
  const int* cnt = blockIdx.x ? cnt1 : cnt0;
  int n          = blockIdx.x ? n1   : n0;
  int* off       = blockIdx.x ? off1 : off0;
  __shared__ int wsum_s[16];
  __shared__ int carry_s;
  int t = threadIdx.x, lane = t & 63, wv = t >> 6;
  if (t == 0) carry_s = 0;
  __syncthreads();
  for (int base = 0; base < n; base += 1024 * 8) {
    int v[8];
    int s = 0;
    int i0 = base + t * 8;
#pragma unroll
    for (int k = 0; k < 8; ++k) {
      int idx = i0 + k;
      v[k] = (idx < n) ? cnt[idx] : 0;
      s += v[k];
    }
    int incl = s;
#pragma unroll
    for (int d = 1; d < 64; d <<= 1) {
      int t2 = __shfl_up(incl, d, 64);
      if (lane >= d) incl += t2;
    }
    if (lane == 63) wsum_s[wv] = incl;
    __syncthreads();
    int woff = 0, total = 0;
#pragma unroll
    for (int w = 0; w < 16; ++w) {
      int ws_v = wsum_s[w];
      woff += (w < wv) ? ws_v : 0;
      total += ws_v;
    }
    int excl = carry_s + woff + incl - s;
#pragma unroll
    for (int k = 0; k < 8; ++k) {
      int idx = i0 + k;
      if (idx < n) off[idx] = excl;
      excl += v[k];
    }
    __syncthreads();
    if (t == 0) carry_s += total;
    __syncthreads();
  }
  if (t == 0) off[n] = carry_s;
}

// --- K4: fused {outer products | atomic-free scatter} ---------------------------
#define GRID_OUT 256
#define GS_OUT 85
#define OCH 32
__global__ void k_fused_os(const float* __restrict__ x, const float* __restrict__ inv_norm,
                           const int* __restrict__ du, float* __restrict__ part,
                           const int* __restrict__ u, const int* __restrict__ it,
                           const unsigned short* __restrict__ ru_,
                           const unsigned short* __restrict__ ri_,
                           const int* __restrict__ uoff, const int* __restrict__ ioff, int E,
                           int* __restrict__ uev, unsigned long long* __restrict__ iue) {
  __shared__ float rows_s[OCH * DD];
  __shared__ float w_s[OCH];
  if ((int)blockIdx.x >= GRID_OUT) {
    // ---- scatter path ----
    int bloc = (int)blockIdx.x - GRID_OUT;
    int nb = (int)gridDim.x - GRID_OUT;
    int t = bloc * blockDim.x + threadIdx.x;
    int stride = nb * blockDim.x;
    for (int e = t; e < E; e += stride) {
      int uu = __builtin_nontemporal_load(&u[e]);
      int ii = __builtin_nontemporal_load(&it[e]);
      int pu = uoff[uu] + (int)__builtin_nontemporal_load(&ru_[e]);
      int pi = ioff[ii] + (int)__builtin_nontemporal_load(&ri_[e]);
      uev[pu] = ii;
      iue[pi] = (unsigned long long)(unsigned)uu |
                ((unsigned long long)(unsigned)pu << 32);
    }
    return;
  }
  // ---- outer path ----
  bool isT = (int)blockIdx.x >= GS_OUT;
  int bloc = isT ? (int)blockIdx.x - GS_OUT : (int)blockIdx.x;
  int nb   = isT ? (GRID_OUT - GS_OUT) : GS_OUT;
  int nrows = isT ? NU : NI;
  int row0  = isT ? 0 : NU;
  int t = threadIdx.x;
  int a0 = (t >> 4) << 2;
  int b0 = (t & 15) << 2;
  float acc[4][4];
#pragma unroll
  for (int i = 0; i < 4; ++i)
#pragma unroll
    for (int j = 0; j < 4; ++j) acc[i][j] = 0.f;
  int nch = (nrows + OCH - 1) / OCH;
  int limit = row0 + nrows;
  for (int ch = bloc; ch < nch; ch += nb) {
    int rbase = row0 + ch * OCH;
    __syncthreads();
    {
      const float4* src = (const float4*)(x + (size_t)rbase * DD);
      float4* dst = (float4*)rows_s;
      int r1 = rbase + (t >> 4);
      dst[t] = (r1 < limit) ? src[t] : make_float4(0.f, 0.f, 0.f, 0.f);
      int r2 = rbase + ((t + 256) >> 4);
      dst[t + 256] = (r2 < limit) ? src[t + 256] : make_float4(0.f, 0.f, 0.f, 0.f);
      if (t < OCH) {
        int r = rbase + t;
        float w = 0.f;
        if (r < limit) {
          w = inv_norm[r];
          if (isT) w /= fmaxf((float)NI - (float)du[r], 1.0f);
        }
        w_s[t] = w;
      }
    }
    __syncthreads();
#pragma unroll 8
    for (int r = 0; r < OCH; ++r) {
      float w = w_s[r];
      const float4 av = *(const float4*)(rows_s + r * DD + a0);
      const float4 bv = *(const float4*)(rows_s + r * DD + b0);
      float wa0 = av.x * w, wa1 = av.y * w, wa2 = av.z * w, wa3 = av.w * w;
      acc[0][0] += wa0 * bv.x; acc[0][1] += wa0 * bv.y; acc[0][2] += wa0 * bv.z; acc[0][3] += wa0 * bv.w;
      acc[1][0] += wa1 * bv.x; acc[1][1] += wa1 * bv.y; acc[1][2] += wa1 * bv.z; acc[1][3] += wa1 * bv.w;
      acc[2][0] += wa2 * bv.x; acc[2][1] += wa2 * bv.y; acc[2][2] += wa2 * bv.z; acc[2][3] += wa2 * bv.w;
      acc[3][0] += wa3 * bv.x; acc[3][1] += wa3 * bv.y; acc[3][2] += wa3 * bv.z; acc[3][3] += wa3 * bv.w;
    }
  }
  float* dst = part + (size_t)blockIdx.x * (DD * DD);
#pragma unroll
  for (int i = 0; i < 4; ++i)
    *(float4*)(dst + (size_t)(a0 + i) * DD + b0) =
        make_float4(acc[i][0], acc[i][1], acc[i][2], acc[i][3]);
}

// --- K6b: reduce partials into Smat/Tmat ------------------------------------------
__global__ void k_redST(const float* __restrict__ part,
                        float* __restrict__ Smat, float* __restrict__ Tmat) {
  int k = blockIdx.x * blockDim.x + threadIdx.x;
  if (k < DD * DD) {
    float s = 0.f;
    for (int b = 0; b < GS_OUT; ++b) s += part[(size_t)b * (DD * DD) + k];
    Smat[k] = s;
  } else {
    int kk = k - DD * DD;
    float s = 0.f;
    for (int b = GS_OUT; b < GRID_OUT; ++b) s += part[(size_t)b * (DD * DD) + kk];
    Tmat[kk] = s;
  }
}

// --- K6c: xs/xt matvec -> out ------------------------------------------------------
__global__ void k_matvec(const float* __restrict__ x, const float* __restrict__ inv_norm,
                         const float* __restrict__ Smat, const float* __restrict__ Tmat,
                         float* __restrict__ out, int gU) {
  bool isI = (int)blockIdx.x >= gU;
  const float* M = isI ? Tmat : Smat;
  int row0  = isI ? NU : 0;
  int nrows = isI ? NI : NU;
  int bloc  = isI ? (int)blockIdx.x - gU : (int)blockIdx.x;
  int nb    = isI ? (int)gridDim.x - gU : gU;
  int lane = threadIdx.x & 63;
  float m_reg[DD];
#pragma unroll
  for (int a = 0; a < DD; ++a) m_reg[a] = M[a * DD + lane];
  int wid = bloc * (blockDim.x >> 6) + (threadIdx.x >> 6);
  int nw  = nb * (blockDim.x >> 6);
  for (int rr = wid; rr < nrows; rr += nw) {
    int r = row0 + rr;
    float v = x[(size_t)r * DD + lane] * inv_norm[r];
    float a0 = 0.f, a1 = 0.f, a2 = 0.f, a3 = 0.f;
#pragma unroll
    for (int a = 0; a < DD; a += 4) {
      a0 += __shfl(v, a)     * m_reg[a];
      a1 += __shfl(v, a + 1) * m_reg[a + 1];
      a2 += __shfl(v, a + 2) * m_reg[a + 2];
      a3 += __shfl(v, a + 3) * m_reg[a + 3];
    }
    out[(size_t)r * DD + lane] = (a0 + a1) + (a2 + a3);
  }
}

// --- K7: per-user pass — fp16 gathers, 8 edges/iter (2 loads in flight) -------------
__global__ void k_user6(const float* __restrict__ x, const float* __restrict__ inv_norm,
                        const float* __restrict__ nrm, const h4* __restrict__ xnih,
                        const int* __restrict__ uoff, const int* __restrict__ uev,
                        const float* __restrict__ sum_xi, const float* __restrict__ sum_vi,
                        float* __restrict__ d_raw, float4* __restrict__ usc,
                        float* __restrict__ out,
                        float* __restrict__ Gx, float* __restrict__ Gv, float* __restrict__ Gb) {
  __shared__ float gx_s[DD], gv_s[DD], gb_s;
  if (threadIdx.x < DD) { gx_s[threadIdx.x] = 0.f; gv_s[threadIdx.x] = 0.f; }
  if (threadIdx.x == 0) gb_s = 0.f;
  __syncthreads();
  int lane = threadIdx.x & 63;
  int g = lane >> 4, c = lane & 15;
  float gmask = (g == 0) ? 1.f : 0.f;
  int wid = blockIdx.x * (blockDim.x >> 6) + (threadIdx.x >> 6);
  int nw  = gridDim.x * (blockDim.x >> 6);
  const float4 sx4  = *(const float4*)(sum_xi + 4 * c);
  const float4 svl4 = *(const float4*)(sum_vi + 4 * c);
  float gxa0=0,gxa1=0,gxa2=0,gxa3=0, gva0=0,gva1=0,gva2=0,gva3=0, gb=0.f;
  for (int uu = wid; uu < NU; uu += nw) {
    size_t ru = (size_t)uu * DD;
    int beg = uoff[uu], end2 = uoff[uu + 1];
    int deg = end2 - beg;
    float a1 = 1.0f / fmaxf((float)deg, 1.0f);
    float a2 = 1.0f / fmaxf((float)(NI - deg), 1.0f);
    float invu = inv_norm[uu];
    const float4 v4 = *(const float4*)(x + ru + 4 * c);
    float4 xu4 = make_float4(v4.x*invu, v4.y*invu, v4.z*invu, v4.w*invu);
    float Av0=0,Av1=0,Av2=0,Av3=0, sv0=0,sv1=0,sv2=0,sv3=0;
    float sA = 0.f;
    for (int base = beg; base < end2; base += 64) {
      int nb2 = end2 - base; if (nb2 > 64) nb2 = 64;
      int ii_l = 0; float nc_l = 0.f;
      if (lane < nb2) {
        ii_l = uev[base + lane];
        nc_l = nrm[ii_l];
      }
      for (int k0 = 0; k0 < nb2; k0 += 8) {
        int ea = k0 + g, eb = k0 + 4 + g;
        int   iia = __shfl(ii_l, ea), iib = __shfl(ii_l, eb);
        float nca = __shfl(nc_l, ea), ncb = __shfl(nc_l, eb);
        float fa = (ea < nb2) ? 1.f : 0.f;
        float fb = (eb < nb2) ? 1.f : 0.f;
        h4 hva = xnih[(size_t)iia * 16 + c];
        h4 hvb = xnih[(size_t)iib * 16 + c];
        float a0r = (float)hva.x, a1r = (float)hva.y, a2r = (float)hva.z, a3r = (float)hva.w;
        float b0r = (float)hvb.x, b1r = (float)hvb.y, b2r = (float)hvb.z, b3r = (float)hvb.w;
        float pa = xu4.x*a0r + xu4.y*a1r + xu4.z*a2r + xu4.w*a3r;
        float pb = xu4.x*b0r + xu4.y*b1r + xu4.z*b2r + xu4.w*b3r;
        float da = fa * rsum16(pa);
        float db = fb * rsum16(pb);
        float wa = da * nca, wb = db * ncb;
        Av0 += wa*a0r + wb*b0r; Av1 += wa*a1r + wb*b1r;
        Av2 += wa*a2r + wb*b2r; Av3 += wa*a3r + wb*b3r;
        sv0 += nca*a0r + ncb*b0r; sv1 += nca*a1r + ncb*b1r;
        sv2 += nca*a2r + ncb*b2r; sv3 += nca*a3r + ncb*b3r;
        sA += da + db;
        if (c == 0) {
          if (ea < nb2) d_raw[base + ea] = da;
          if (eb < nb2) d_raw[base + eb] = db;
        }
      }
    }
    sA  = xgrp2(sA);
    Av0 = xgrp2(Av0); Av1 = xgrp2(Av1); Av2 = xgrp2(Av2); Av3 = xgrp2(Av3);
    sv0 = xgrp2(sv0); sv1 = xgrp2(sv1); sv2 = xgrp2(sv2); sv3 = xgrp2(sv3);
    float bp = sA * a1;
    float pbn = xu4.x*sx4.x + xu4.y*sx4.y + xu4.z*sx4.z + xu4.w*sx4.w;
    float bn = (rsum16(pbn) - sA) * a2;
    float s1 = (ALPHA_C - bn) * a1;
    float s2 = (bp + ALPHA_C) * a2;
    if (lane == 0) usc[uu] = make_float4(a1, a2, s1, s2);
    const float4 xs4 = *(const float4*)(out + ru + 4 * c);
    float c12 = s1 + s2, a12 = a1 - a2;
    float rden = 1.0f / (2.0f * fmaxf(bp - bn + ALPHA_C, EPS_CLAMP));
    float o0 = (Av0 * a12 + sv0 * c12 + xs4.x * a2 - svl4.x * s2) * rden;
    float o1 = (Av1 * a12 + sv1 * c12 + xs4.y * a2 - svl4.y * s2) * rden;
    float o2 = (Av2 * a12 + sv2 * c12 + xs4.z * a2 - svl4.z * s2) * rden;
    float o3 = (Av3 * a12 + sv3 * c12 + xs4.w * a2 - svl4.w * s2) * rden;
    if (g == 0) *(float4*)(out + ru + 4 * c) = make_float4(o0, o1, o2, o3);
    float t2 = a2 * gmask, t3 = s2 * gmask;
    gxa0 += t2 * xu4.x; gxa1 += t2 * xu4.y; gxa2 += t2 * xu4.z; gxa3 += t2 * xu4.w;
    gva0 += t3 * v4.x;  gva1 += t3 * v4.y;  gva2 += t3 * v4.z;  gva3 += t3 * v4.w;
    if (lane == 0) gb += s2;
  }
  if (g == 0) {
    atomicAdd(&gx_s[4*c+0], gxa0); atomicAdd(&gx_s[4*c+1], gxa1);
    atomicAdd(&gx_s[4*c+2], gxa2); atomicAdd(&gx_s[4*c+3], gxa3);
    atomicAdd(&gv_s[4*c+0], gva0); atomicAdd(&gv_s[4*c+1], gva1);
    atomicAdd(&gv_s[4*c+2], gva2); atomicAdd(&gv_s[4*c+3], gva3);
  }
  if (lane == 0) atomicAdd(&gb_s, gb);
  __syncthreads();
  if (threadIdx.x < DD) {
    atomicAdd(&Gx[threadIdx.x], gx_s[threadIdx.x]);
    atomicAdd(&Gv[threadIdx.x], gv_s[threadIdx.x]);
  }
  if (threadIdx.x == 0) atomicAdd(Gb, gb_s);
}

// --- K8: per-item pass — fp16 gathers, 8 edges/iter ----------------------------------
__global__ void k_item6(const float* __restrict__ x, const float* __restrict__ inv_norm,
                        const h4* __restrict__ vuh,
                        const int* __restrict__ ioff, const uint2* __restrict__ iue,
                        const float* __restrict__ d_raw, const float4* __restrict__ usc,
                        const float* __restrict__ Gx, const float* __restrict__ Gv,
                        const float* __restrict__ Gb, float* __restrict__ out) {
  int lane = threadIdx.x & 63;
  int g = lane >> 4, c = lane & 15;
  int wid = blockIdx.x * (blockDim.x >> 6) + (threadIdx.x >> 6);
  int nw  = gridDim.x * (blockDim.x >> 6);
  const float4 Gx4 = *(const float4*)(Gx + 4 * c);
  const float4 Gv4 = *(const float4*)(Gv + 4 * c);
  float gb = *Gb;
  for (int j = wid; j < NI; j += nw) {
    int r = NU + j;
    size_t rr = (size_t)r * DD;
    float invi = inv_norm[r];
    const float4 vi4 = *(const float4*)(x + rr + 4 * c);
    float4 xi4 = make_float4(vi4.x*invi, vi4.y*invi, vi4.z*invi, vi4.w*invi);
    int beg = ioff[j], end2 = ioff[j + 1];
    float W0=0,W1=0,W2=0,W3=0, q1=0.f, q2=0.f;
    for (int base = beg; base < end2; base += 64) {
      int nb2 = end2 - base; if (nb2 > 64) nb2 = 64;
      int uu_l = 0; float glx = 0.f;
      if (lane < nb2) {
        uint2 m = iue[base + lane];
        uu_l = (int)m.x;
        float d = d_raw[m.y];
        float4 cc = usc[uu_l];
        float t1 = d * cc.x + cc.z;
        float t2 = d * cc.y - cc.w;
        q1 += t1; q2 += t2;
        glx = t1 - t2;
      }
      for (int k0 = 0; k0 < nb2; k0 += 8) {
        int ea = k0 + g, eb = k0 + 4 + g;
        int   ua = __shfl(uu_l, ea), ub = __shfl(uu_l, eb);
        float ga = __shfl(glx, ea),  gbn = __shfl(glx, eb);
        h4 hva = vuh[(size_t)ua * 16 + c];
        h4 hvb = vuh[(size_t)ub * 16 + c];
        W0 += ga * (float)hva.x + gbn * (float)hvb.x;
        W1 += ga * (float)hva.y + gbn * (float)hvb.y;
        W2 += ga * (float)hva.z + gbn * (float)hvb.z;
        W3 += ga * (float)hva.w + gbn * (float)hvb.w;
      }
    }
    q1 = wsum(q1); q2 = wsum(q2);
    W0 = xgrp2(W0); W1 = xgrp2(W1); W2 = xgrp2(W2); W3 = xgrp2(W3);
    float pd = xi4.x*Gx4.x + xi4.y*Gx4.y + xi4.z*Gx4.z + xi4.w*Gx4.w;
    float di1 = q1;
    float di2 = -rsum16(pd) + q2 + gb;
    const float4 xt4 = *(const float4*)(out + rr + 4 * c);
    float rden = 1.0f / (fmaxf(di1, EPS_CLAMP) + fmaxf(di2, EPS_CLAMP));
    float o0 = (W0 + xt4.x - Gv4.x) * rden;
    float o1 = (W1 + xt4.y - Gv4.y) * rden;
    float o2 = (W2 + xt4.z - Gv4.z) * rden;
    float o3 = (W3 + xt4.w - Gv4.w) * rden;
    if (g == 0) *(float4*)(out + rr + 4 * c) = make_float4(o0, o1, o2, o3);
  }
}

extern "C" void kernel_launch(void* const* d_in, const int* in_sizes, int n_in,
                              void* d_out, int out_size, void* d_ws, size_t ws_size,
                              hipStream_t stream) {
  const float* x  = (const float*)d_in[0];
  const int*   u  = (const int*)d_in[1];
  const int*   it = (const int*)d_in[2];
  float* out = (float*)d_out;
  const int E = in_sizes[1];

  char* wsb = (char*)d_ws;
  size_t off = 0;
  auto alloc = [&](size_t elems) { void* p = wsb + off; off += elems * 4; return p; };

  // zero-init region (contiguous, first)
  int*   du     = (int*)alloc(100016);
  int*   di     = (int*)alloc(50016);
  float* sum_xi = (float*)alloc(64);
  float* sum_vi = (float*)alloc(64);
  float* Gx     = (float*)alloc(64);
  float* Gv     = (float*)alloc(64);
  float* Gb     = (float*)alloc(16);
  size_t zero_bytes = off;

  float* Smat   = (float*)alloc(4096);
  float* Tmat   = (float*)alloc(4096);
  float* part   = (float*)alloc((size_t)GRID_OUT * 4096);
  float*  inv_norm = (float*)alloc(150016);
  float*  nrm      = (float*)alloc(50016);
  h4*     xnih     = (h4*)alloc((size_t)NI * 32);   // NI*64 halfs
  h4*     vuh      = (h4*)alloc((size_t)NU * 32);   // NU*64 halfs
  int*    uoff     = (int*)alloc(100016);
  int*    ioff     = (int*)alloc(50016);
  unsigned short* ru_ = (unsigned short*)alloc(500000);
  unsigned short* ri_ = (unsigned short*)alloc(500000);
  int*    uev      = (int*)alloc(1000000);
  unsigned long long* iue = (unsigned long long*)alloc(2000000);
  float*  d_raw    = (float*)alloc(1000000);
  float4* usc      = (float4*)alloc(400000);

  hipMemsetAsync(d_ws, 0, zero_bytes, stream);

  k_norm_count<<<GN_NORM + 1024, 256, 0, stream>>>(x, inv_norm, nrm, xnih, vuh,
                                                   sum_xi, sum_vi,
                                                   u, it, du, di, ru_, ri_, E);
  k_scan2<<<2, 1024, 0, stream>>>(du, NU, uoff, di, NI, ioff);
  k_fused_os<<<GRID_OUT + 4096, 256, 0, stream>>>(x, inv_norm, du, part,
                                                  u, it, ru_, ri_, uoff, ioff, E,
                                                  uev, iue);
  k_redST<<<32, 256, 0, stream>>>(part, Smat, Tmat);
  k_matvec<<<1536, 256, 0, stream>>>(x, inv_norm, Smat, Tmat, out, 1024);
  k_user6<<<4096, 256, 0, stream>>>(x, inv_norm, nrm, xnih, uoff, uev, sum_xi, sum_vi,
                                    d_raw, usc, out, Gx, Gv, Gb);
  k_item6<<<4096, 256, 0, stream>>>(x, inv_norm, vuh, ioff, (const uint2*)iue, d_raw, usc,
                                    Gx, Gv, Gb, out);
}

// Round 13
// 591.153 us; speedup vs baseline: 1.1041x; 1.1041x over previous
//
#include <hip/hip_runtime.h>

#define NU 100000
#define NI 50000
#define DD 64
#define ALPHA_C 1.0f
#define EPS_CLAMP 1e-6f

typedef _Float16 h4 __attribute__((ext_vector_type(4)));

__device__ __forceinline__ float rsum16(float v) {
  v += __shfl_xor(v, 1, 64);
  v += __shfl_xor(v, 2, 64);
  v += __shfl_xor(v, 4, 64);
  v += __shfl_xor(v, 8, 64);
  return v;
}
__device__ __forceinline__ float xgrp2(float v) {
  v += __shfl_xor(v, 16, 64);
  v += __shfl_xor(v, 32, 64);
  return v;
}
__device__ __forceinline__ float wsum(float v) { return xgrp2(rsum16(v)); }

// --- K1: fused {norms + item sums + fp16 tables | degree counts + ranks} -------
#define GN_NORM 1024
__global__ void k_norm_count(const float* __restrict__ x, float* __restrict__ inv_norm,
                             float* __restrict__ nrm, h4* __restrict__ xnih,
                             h4* __restrict__ vuh,
                             float* __restrict__ sum_xi, float* __restrict__ sum_vi,
                             const int* __restrict__ u, const int* __restrict__ it,
                             int* __restrict__ du, int* __restrict__ di,
                             unsigned short* __restrict__ ru_, unsigned short* __restrict__ ri_,
                             int E) {
  if ((int)blockIdx.x >= GN_NORM) {
    int bloc = (int)blockIdx.x - GN_NORM;
    int nb = (int)gridDim.x - GN_NORM;
    int t = bloc * blockDim.x + threadIdx.x;
    int stride = nb * blockDim.x;
    for (int e = t; e < E; e += stride) {
      int uu = __builtin_nontemporal_load(&u[e]);
      int ii = __builtin_nontemporal_load(&it[e]);
      ru_[e] = (unsigned short)atomicAdd(&du[uu], 1);
      ri_[e] = (unsigned short)atomicAdd(&di[ii], 1);
    }
    return;
  }
  __shared__ float sx_s[DD], sv_s[DD];
  if (threadIdx.x < DD) { sx_s[threadIdx.x] = 0.f; sv_s[threadIdx.x] = 0.f; }
  __syncthreads();
  int lane = threadIdx.x & 63;
  int g = lane >> 4, c = lane & 15;
  int wid = blockIdx.x * 4 + (threadIdx.x >> 6);
  int nw  = GN_NORM * 4;
  float sx0=0,sx1=0,sx2=0,sx3=0, sv0=0,sv1=0,sv2=0,sv3=0;
  for (int rb = wid * 4; rb < NU + NI; rb += nw * 4) {
    int r = rb + g;
    const float4 v4 = *(const float4*)(x + (size_t)r * DD + 4 * c);
    float p = v4.x*v4.x + v4.y*v4.y + v4.z*v4.z + v4.w*v4.w;
    p = rsum16(p);
    float nc  = fmaxf(sqrtf(p), 1e-12f);
    float inv = 1.0f / nc;
    if (c == 0) inv_norm[r] = inv;
    if (r >= NU) {
      int j = r - NU;
      if (c == 0) nrm[j] = nc;
      float xn0 = v4.x*inv, xn1 = v4.y*inv, xn2 = v4.z*inv, xn3 = v4.w*inv;
      h4 hw = { (_Float16)xn0, (_Float16)xn1, (_Float16)xn2, (_Float16)xn3 };
      xnih[(size_t)j * 16 + c] = hw;
      sv0 += v4.x; sv1 += v4.y; sv2 += v4.z; sv3 += v4.w;
      sx0 += xn0;  sx1 += xn1;  sx2 += xn2;  sx3 += xn3;
    } else {
      h4 hw = { (_Float16)v4.x, (_Float16)v4.y, (_Float16)v4.z, (_Float16)v4.w };
      vuh[(size_t)r * 16 + c] = hw;
    }
  }
  atomicAdd(&sx_s[4*c+0], sx0); atomicAdd(&sx_s[4*c+1], sx1);
  atomicAdd(&sx_s[4*c+2], sx2); atomicAdd(&sx_s[4*c+3], sx3);
  atomicAdd(&sv_s[4*c+0], sv0); atomicAdd(&sv_s[4*c+1], sv1);
  atomicAdd(&sv_s[4*c+2], sv2); atomicAdd(&sv_s[4*c+3], sv3);
  __syncthreads();
  if (threadIdx.x < DD) {
    atomicAdd(&sum_xi[threadIdx.x], sx_s[threadIdx.x]);
    atomicAdd(&sum_vi[threadIdx.x], sv_s[threadIdx.x]);
  }
}

// --- K3: two single-block exclusive scans --------------------------------------
__global__ void k_scan2(const int* __restrict__ cnt0, int n0, int* __restrict__ off0,
                        const int* __restrict__ cnt1, int n1, int* __restrict__ off1) {
  const int* cnt = blockIdx.x ? cnt1 : cnt0;
  int n          = blockIdx.x ? n1   : n0;
  int* off       = blockIdx.x ? off1 : off0;
  __shared__ int wsum_s[16];
  __shared__ int carry_s;
  int t = threadIdx.x, lane = t & 63, wv = t >> 6;
  if (t == 0) carry_s = 0;
  __syncthreads();
  for (int base = 0; base < n; base += 1024 * 8) {
    int v[8];
    int s = 0;
    int i0 = base + t * 8;
#pragma unroll
    for (int k = 0; k < 8; ++k) {
      int idx = i0 + k;
      v[k] = (idx < n) ? cnt[idx] : 0;
      s += v[k];
    }
    int incl = s;
#pragma unroll
    for (int d = 1; d < 64; d <<= 1) {
      int t2 = __shfl_up(incl, d, 64);
      if (lane >= d) incl += t2;
    }
    if (lane == 63) wsum_s[wv] = incl;
    __syncthreads();
    int woff = 0, total = 0;
#pragma unroll
    for (int w = 0; w < 16; ++w) {
      int ws_v = wsum_s[w];
      woff += (w < wv) ? ws_v : 0;
      total += ws_v;
    }
    int excl = carry_s + woff + incl - s;
#pragma unroll
    for (int k = 0; k < 8; ++k) {
      int idx = i0 + k;
      if (idx < n) off[idx] = excl;
      excl += v[k];
    }
    __syncthreads();
    if (t == 0) carry_s += total;
    __syncthreads();
  }
  if (t == 0) off[n] = carry_s;
}

// --- K4: fused {outer products | atomic-free scatter} ---------------------------
#define GRID_OUT 256
#define GS_OUT 85
#define OCH 32
__global__ void k_fused_os(const float* __restrict__ x, const float* __restrict__ inv_norm,
                           const int* __restrict__ du, float* __restrict__ part,
                           const int* __restrict__ u, const int* __restrict__ it,
                           const unsigned short* __restrict__ ru_,
                           const unsigned short* __restrict__ ri_,
                           const int* __restrict__ uoff, const int* __restrict__ ioff, int E,
                           int* __restrict__ uev, unsigned long long* __restrict__ iue) {
  __shared__ float rows_s[OCH * DD];
  __shared__ float w_s[OCH];
  if ((int)blockIdx.x >= GRID_OUT) {
    int bloc = (int)blockIdx.x - GRID_OUT;
    int nb = (int)gridDim.x - GRID_OUT;
    int t = bloc * blockDim.x + threadIdx.x;
    int stride = nb * blockDim.x;
    for (int e = t; e < E; e += stride) {
      int uu = __builtin_nontemporal_load(&u[e]);
      int ii = __builtin_nontemporal_load(&it[e]);
      int pu = uoff[uu] + (int)__builtin_nontemporal_load(&ru_[e]);
      int pi = ioff[ii] + (int)__builtin_nontemporal_load(&ri_[e]);
      uev[pu] = ii;
      iue[pi] = (unsigned long long)(unsigned)uu |
                ((unsigned long long)(unsigned)pu << 32);
    }
    return;
  }
  bool isT = (int)blockIdx.x >= GS_OUT;
  int bloc = isT ? (int)blockIdx.x - GS_OUT : (int)blockIdx.x;
  int nb   = isT ? (GRID_OUT - GS_OUT) : GS_OUT;
  int nrows = isT ? NU : NI;
  int row0  = isT ? 0 : NU;
  int t = threadIdx.x;
  int a0 = (t >> 4) << 2;
  int b0 = (t & 15) << 2;
  float acc[4][4];
#pragma unroll
  for (int i = 0; i < 4; ++i)
#pragma unroll
    for (int j = 0; j < 4; ++j) acc[i][j] = 0.f;
  int nch = (nrows + OCH - 1) / OCH;
  int limit = row0 + nrows;
  for (int ch = bloc; ch < nch; ch += nb) {
    int rbase = row0 + ch * OCH;
    __syncthreads();
    {
      const float4* src = (const float4*)(x + (size_t)rbase * DD);
      float4* dst = (float4*)rows_s;
      int r1 = rbase + (t >> 4);
      dst[t] = (r1 < limit) ? src[t] : make_float4(0.f, 0.f, 0.f, 0.f);
      int r2 = rbase + ((t + 256) >> 4);
      dst[t + 256] = (r2 < limit) ? src[t + 256] : make_float4(0.f, 0.f, 0.f, 0.f);
      if (t < OCH) {
        int r = rbase + t;
        float w = 0.f;
        if (r < limit) {
          w = inv_norm[r];
          if (isT) w /= fmaxf((float)NI - (float)du[r], 1.0f);
        }
        w_s[t] = w;
      }
    }
    __syncthreads();
#pragma unroll 8
    for (int r = 0; r < OCH; ++r) {
      float w = w_s[r];
      const float4 av = *(const float4*)(rows_s + r * DD + a0);
      const float4 bv = *(const float4*)(rows_s + r * DD + b0);
      float wa0 = av.x * w, wa1 = av.y * w, wa2 = av.z * w, wa3 = av.w * w;
      acc[0][0] += wa0 * bv.x; acc[0][1] += wa0 * bv.y; acc[0][2] += wa0 * bv.z; acc[0][3] += wa0 * bv.w;
      acc[1][0] += wa1 * bv.x; acc[1][1] += wa1 * bv.y; acc[1][2] += wa1 * bv.z; acc[1][3] += wa1 * bv.w;
      acc[2][0] += wa2 * bv.x; acc[2][1] += wa2 * bv.y; acc[2][2] += wa2 * bv.z; acc[2][3] += wa2 * bv.w;
      acc[3][0] += wa3 * bv.x; acc[3][1] += wa3 * bv.y; acc[3][2] += wa3 * bv.z; acc[3][3] += wa3 * bv.w;
    }
  }
  float* dst = part + (size_t)blockIdx.x * (DD * DD);
#pragma unroll
  for (int i = 0; i < 4; ++i)
    *(float4*)(dst + (size_t)(a0 + i) * DD + b0) =
        make_float4(acc[i][0], acc[i][1], acc[i][2], acc[i][3]);
}

// --- K6b: reduce partials into Smat/Tmat ------------------------------------------
__global__ void k_redST(const float* __restrict__ part,
                        float* __restrict__ Smat, float* __restrict__ Tmat) {
  int k = blockIdx.x * blockDim.x + threadIdx.x;
  if (k < DD * DD) {
    float s = 0.f;
    for (int b = 0; b < GS_OUT; ++b) s += part[(size_t)b * (DD * DD) + k];
    Smat[k] = s;
  } else {
    int kk = k - DD * DD;
    float s = 0.f;
    for (int b = GS_OUT; b < GRID_OUT; ++b) s += part[(size_t)b * (DD * DD) + kk];
    Tmat[kk] = s;
  }
}

// --- K6c: xs/xt matvec -> out ------------------------------------------------------
__global__ void k_matvec(const float* __restrict__ x, const float* __restrict__ inv_norm,
                         const float* __restrict__ Smat, const float* __restrict__ Tmat,
                         float* __restrict__ out, int gU) {
  bool isI = (int)blockIdx.x >= gU;
  const float* M = isI ? Tmat : Smat;
  int row0  = isI ? NU : 0;
  int nrows = isI ? NI : NU;
  int bloc  = isI ? (int)blockIdx.x - gU : (int)blockIdx.x;
  int nb    = isI ? (int)gridDim.x - gU : gU;
  int lane = threadIdx.x & 63;
  float m_reg[DD];
#pragma unroll
  for (int a = 0; a < DD; ++a) m_reg[a] = M[a * DD + lane];
  int wid = bloc * (blockDim.x >> 6) + (threadIdx.x >> 6);
  int nw  = nb * (blockDim.x >> 6);
  for (int rr = wid; rr < nrows; rr += nw) {
    int r = row0 + rr;
    float v = x[(size_t)r * DD + lane] * inv_norm[r];
    float a0 = 0.f, a1 = 0.f, a2 = 0.f, a3 = 0.f;
#pragma unroll
    for (int a = 0; a < DD; a += 4) {
      a0 += __shfl(v, a)     * m_reg[a];
      a1 += __shfl(v, a + 1) * m_reg[a + 1];
      a2 += __shfl(v, a + 2) * m_reg[a + 2];
      a3 += __shfl(v, a + 3) * m_reg[a + 3];
    }
    out[(size_t)r * DD + lane] = (a0 + a1) + (a2 + a3);
  }
}

// --- K7: per-user pass — 2 users/wave, 4 edges/iter each (2 loads in flight) --------
__global__ void k_user7(const float* __restrict__ x, const float* __restrict__ inv_norm,
                        const float* __restrict__ nrm, const h4* __restrict__ xnih,
                        const int* __restrict__ uoff, const int* __restrict__ uev,
                        const float* __restrict__ sum_xi, const float* __restrict__ sum_vi,
                        float* __restrict__ d_raw, float4* __restrict__ usc,
                        float* __restrict__ out,
                        float* __restrict__ Gx, float* __restrict__ Gv, float* __restrict__ Gb) {
  __shared__ float gx_s[DD], gv_s[DD], gb_s;
  if (threadIdx.x < DD) { gx_s[threadIdx.x] = 0.f; gv_s[threadIdx.x] = 0.f; }
  if (threadIdx.x == 0) gb_s = 0.f;
  __syncthreads();
  int lane = threadIdx.x & 63;
  int g = lane >> 4, c = lane & 15;
  float gmask = (g == 0) ? 1.f : 0.f;
  int wid = blockIdx.x * (blockDim.x >> 6) + (threadIdx.x >> 6);
  int nw  = gridDim.x * (blockDim.x >> 6);
  const float4 sx4  = *(const float4*)(sum_xi + 4 * c);
  const float4 svl4 = *(const float4*)(sum_vi + 4 * c);
  float gxa0=0,gxa1=0,gxa2=0,gxa3=0, gva0=0,gva1=0,gva2=0,gva3=0, gb=0.f;
  const int NP = NU / 2;
  for (int pid = wid; pid < NP; pid += nw) {
    int u0 = pid << 1;
    int beg0 = uoff[u0], end0 = uoff[u0 + 1], end1 = uoff[u0 + 2];
    int beg1 = end0;
    int degs[2] = { end0 - beg0, end1 - beg1 };
    int begs[2] = { beg0, beg1 };
    float a1c[2], a2c[2];
    float4 v4[2], xu4[2];
#pragma unroll
    for (int p = 0; p < 2; ++p) {
      a1c[p] = 1.0f / fmaxf((float)degs[p], 1.0f);
      a2c[p] = 1.0f / fmaxf((float)(NI - degs[p]), 1.0f);
      float invu = inv_norm[u0 + p];
      v4[p] = *(const float4*)(x + (size_t)(u0 + p) * DD + 4 * c);
      xu4[p] = make_float4(v4[p].x*invu, v4[p].y*invu, v4[p].z*invu, v4[p].w*invu);
    }
    float Av[2][4] = {{0,0,0,0},{0,0,0,0}};
    float sv[2][4] = {{0,0,0,0},{0,0,0,0}};
    float sA[2] = {0, 0};
    int nb0t = (degs[0] + 63) >> 6, nb1t = (degs[1] + 63) >> 6;
    int nBat = nb0t > nb1t ? nb0t : nb1t;
    for (int bo = 0; bo < nBat; ++bo) {
      int nbl[2]; int ii_l[2] = {0, 0}; float nc_l[2] = {0.f, 0.f};
#pragma unroll
      for (int p = 0; p < 2; ++p) {
        int base = begs[p] + (bo << 6);
        int nn = degs[p] - (bo << 6);
        nn = nn < 0 ? 0 : (nn > 64 ? 64 : nn);
        nbl[p] = nn;
        if (lane < nn) {
          ii_l[p] = uev[base + lane];
          nc_l[p] = nrm[ii_l[p]];
        }
      }
      int nbmax = nbl[0] > nbl[1] ? nbl[0] : nbl[1];
      for (int k0 = 0; k0 < nbmax; k0 += 4) {
        int e = k0 + g;
        int ia = __shfl(ii_l[0], e);
        int ib = __shfl(ii_l[1], e);
        h4 ha = xnih[(size_t)ia * 16 + c];
        h4 hb = xnih[(size_t)ib * 16 + c];
        float na = __shfl(nc_l[0], e);
        float nbv = __shfl(nc_l[1], e);
        float fa = (e < nbl[0]) ? 1.f : 0.f;
        float fb = (e < nbl[1]) ? 1.f : 0.f;
        float a0r = (float)ha.x, a1r = (float)ha.y, a2r = (float)ha.z, a3r = (float)ha.w;
        float b0r = (float)hb.x, b1r = (float)hb.y, b2r = (float)hb.z, b3r = (float)hb.w;
        float pa = xu4[0].x*a0r + xu4[0].y*a1r + xu4[0].z*a2r + xu4[0].w*a3r;
        float pb = xu4[1].x*b0r + xu4[1].y*b1r + xu4[1].z*b2r + xu4[1].w*b3r;
        float da = fa * rsum16(pa);
        float db = fb * rsum16(pb);
        float wa = da * na, wb = db * nbv;
        Av[0][0] += wa*a0r; Av[0][1] += wa*a1r; Av[0][2] += wa*a2r; Av[0][3] += wa*a3r;
        Av[1][0] += wb*b0r; Av[1][1] += wb*b1r; Av[1][2] += wb*b2r; Av[1][3] += wb*b3r;
        sv[0][0] += na*a0r; sv[0][1] += na*a1r; sv[0][2] += na*a2r; sv[0][3] += na*a3r;
        sv[1][0] += nbv*b0r; sv[1][1] += nbv*b1r; sv[1][2] += nbv*b2r; sv[1][3] += nbv*b3r;
        sA[0] += da; sA[1] += db;
        if (c == 0) {
          if (e < nbl[0]) d_raw[begs[0] + (bo << 6) + e] = da;
          if (e < nbl[1]) d_raw[begs[1] + (bo << 6) + e] = db;
        }
      }
    }
#pragma unroll
    for (int p = 0; p < 2; ++p) {
      float sAp = xgrp2(sA[p]);
      float A0 = xgrp2(Av[p][0]), A1 = xgrp2(Av[p][1]);
      float A2 = xgrp2(Av[p][2]), A3 = xgrp2(Av[p][3]);
      float s0 = xgrp2(sv[p][0]), s1v = xgrp2(sv[p][1]);
      float s2v = xgrp2(sv[p][2]), s3v = xgrp2(sv[p][3]);
      float bp = sAp * a1c[p];
      float pbn = xu4[p].x*sx4.x + xu4[p].y*sx4.y + xu4[p].z*sx4.z + xu4[p].w*sx4.w;
      float bn = (rsum16(pbn) - sAp) * a2c[p];
      float s1 = (ALPHA_C - bn) * a1c[p];
      float s2 = (bp + ALPHA_C) * a2c[p];
      if (lane == 0) usc[u0 + p] = make_float4(a1c[p], a2c[p], s1, s2);
      size_t ru = (size_t)(u0 + p) * DD;
      const float4 xs4 = *(const float4*)(out + ru + 4 * c);
      float c12 = s1 + s2, a12 = a1c[p] - a2c[p];
      float rden = 1.0f / (2.0f * fmaxf(bp - bn + ALPHA_C, EPS_CLAMP));
      float o0 = (A0 * a12 + s0 * c12 + xs4.x * a2c[p] - svl4.x * s2) * rden;
      float o1 = (A1 * a12 + s1v * c12 + xs4.y * a2c[p] - svl4.y * s2) * rden;
      float o2 = (A2 * a12 + s2v * c12 + xs4.z * a2c[p] - svl4.z * s2) * rden;
      float o3 = (A3 * a12 + s3v * c12 + xs4.w * a2c[p] - svl4.w * s2) * rden;
      if (g == 0) *(float4*)(out + ru + 4 * c) = make_float4(o0, o1, o2, o3);
      float t2 = a2c[p] * gmask, t3 = s2 * gmask;
      gxa0 += t2 * xu4[p].x; gxa1 += t2 * xu4[p].y; gxa2 += t2 * xu4[p].z; gxa3 += t2 * xu4[p].w;
      gva0 += t3 * v4[p].x;  gva1 += t3 * v4[p].y;  gva2 += t3 * v4[p].z;  gva3 += t3 * v4[p].w;
      if (lane == 0) gb += s2;
    }
  }
  if (g == 0) {
    atomicAdd(&gx_s[4*c+0], gxa0); atomicAdd(&gx_s[4*c+1], gxa1);
    atomicAdd(&gx_s[4*c+2], gxa2); atomicAdd(&gx_s[4*c+3], gxa3);
    atomicAdd(&gv_s[4*c+0], gva0); atomicAdd(&gv_s[4*c+1], gva1);
    atomicAdd(&gv_s[4*c+2], gva2); atomicAdd(&gv_s[4*c+3], gva3);
  }
  if (lane == 0) atomicAdd(&gb_s, gb);
  __syncthreads();
  if (threadIdx.x < DD) {
    atomicAdd(&Gx[threadIdx.x], gx_s[threadIdx.x]);
    atomicAdd(&Gv[threadIdx.x], gv_s[threadIdx.x]);
  }
  if (threadIdx.x == 0) atomicAdd(Gb, gb_s);
}

// --- K8: per-item pass — 2 items/wave, 4 edges/iter each -----------------------------
__global__ void k_item7(const float* __restrict__ x, const float* __restrict__ inv_norm,
                        const h4* __restrict__ vuh,
                        const int* __restrict__ ioff, const uint2* __restrict__ iue,
                        const float* __restrict__ d_raw, const float4* __restrict__ usc,
                        const float* __restrict__ Gx, const float* __restrict__ Gv,
                        const float* __restrict__ Gb, float* __restrict__ out) {
  int lane = threadIdx.x & 63;
  int g = lane >> 4, c = lane & 15;
  int wid = blockIdx.x * (blockDim.x >> 6) + (threadIdx.x >> 6);
  int nw  = gridDim.x * (blockDim.x >> 6);
  const float4 Gx4 = *(const float4*)(Gx + 4 * c);
  const float4 Gv4 = *(const float4*)(Gv + 4 * c);
  float gbv = *Gb;
  const int NP = NI / 2;
  for (int pid = wid; pid < NP; pid += nw) {
    int j0 = pid << 1;
    int beg0 = ioff[j0], end0 = ioff[j0 + 1], end1 = ioff[j0 + 2];
    int begs[2] = { beg0, end0 };
    int degs[2] = { end0 - beg0, end1 - end0 };
    float4 xi4[2];
#pragma unroll
    for (int p = 0; p < 2; ++p) {
      int r = NU + j0 + p;
      float invi = inv_norm[r];
      const float4 vi4 = *(const float4*)(x + (size_t)r * DD + 4 * c);
      xi4[p] = make_float4(vi4.x*invi, vi4.y*invi, vi4.z*invi, vi4.w*invi);
    }
    float W[2][4] = {{0,0,0,0},{0,0,0,0}};
    float q1[2] = {0.f, 0.f}, q2[2] = {0.f, 0.f};
    int nb0t = (degs[0] + 63) >> 6, nb1t = (degs[1] + 63) >> 6;
    int nBat = nb0t > nb1t ? nb0t : nb1t;
    for (int bo = 0; bo < nBat; ++bo) {
      int nbl[2]; int uu_l[2] = {0, 0}; float glx[2] = {0.f, 0.f};
#pragma unroll
      for (int p = 0; p < 2; ++p) {
        int base = begs[p] + (bo << 6);
        int nn = degs[p] - (bo << 6);
        nn = nn < 0 ? 0 : (nn > 64 ? 64 : nn);
        nbl[p] = nn;
        if (lane < nn) {
          uint2 m = iue[base + lane];
          uu_l[p] = (int)m.x;
          float d = d_raw[m.y];
          float4 cc = usc[uu_l[p]];
          float t1 = d * cc.x + cc.z;
          float t2 = d * cc.y - cc.w;
          q1[p] += t1; q2[p] += t2;
          glx[p] = t1 - t2;
        }
      }
      int nbmax = nbl[0] > nbl[1] ? nbl[0] : nbl[1];
      for (int k0 = 0; k0 < nbmax; k0 += 4) {
        int e = k0 + g;
        int ua = __shfl(uu_l[0], e);
        int ub = __shfl(uu_l[1], e);
        h4 hva = vuh[(size_t)ua * 16 + c];
        h4 hvb = vuh[(size_t)ub * 16 + c];
        float ga = __shfl(glx[0], e);
        float gbn = __shfl(glx[1], e);
        W[0][0] += ga * (float)hva.x; W[0][1] += ga * (float)hva.y;
        W[0][2] += ga * (float)hva.z; W[0][3] += ga * (float)hva.w;
        W[1][0] += gbn * (float)hvb.x; W[1][1] += gbn * (float)hvb.y;
        W[1][2] += gbn * (float)hvb.z; W[1][3] += gbn * (float)hvb.w;
      }
    }
#pragma unroll
    for (int p = 0; p < 2; ++p) {
      float q1p = wsum(q1[p]);
      float q2p = wsum(q2[p]);
      float W0 = xgrp2(W[p][0]), W1 = xgrp2(W[p][1]);
      float W2 = xgrp2(W[p][2]), W3 = xgrp2(W[p][3]);
      float pd = xi4[p].x*Gx4.x + xi4[p].y*Gx4.y + xi4[p].z*Gx4.z + xi4[p].w*Gx4.w;
      float di1 = q1p;
      float di2 = -rsum16(pd) + q2p + gbv;
      size_t rr = (size_t)(NU + j0 + p) * DD;
      const float4 xt4 = *(const float4*)(out + rr + 4 * c);
      float rden = 1.0f / (fmaxf(di1, EPS_CLAMP) + fmaxf(di2, EPS_CLAMP));
      float o0 = (W0 + xt4.x - Gv4.x) * rden;
      float o1 = (W1 + xt4.y - Gv4.y) * rden;
      float o2 = (W2 + xt4.z - Gv4.z) * rden;
      float o3 = (W3 + xt4.w - Gv4.w) * rden;
      if (g == 0) *(float4*)(out + rr + 4 * c) = make_float4(o0, o1, o2, o3);
    }
  }
}

extern "C" void kernel_launch(void* const* d_in, const int* in_sizes, int n_in,
                              void* d_out, int out_size, void* d_ws, size_t ws_size,
                              hipStream_t stream) {
  const float* x  = (const float*)d_in[0];
  const int*   u  = (const int*)d_in[1];
  const int*   it = (const int*)d_in[2];
  float* out = (float*)d_out;
  const int E = in_sizes[1];

  char* wsb = (char*)d_ws;
  size_t off = 0;
  auto alloc = [&](size_t elems) { void* p = wsb + off; off += elems * 4; return p; };

  // zero-init region (contiguous, first)
  int*   du     = (int*)alloc(100016);
  int*   di     = (int*)alloc(50016);
  float* sum_xi = (float*)alloc(64);
  float* sum_vi = (float*)alloc(64);
  float* Gx     = (float*)alloc(64);
  float* Gv     = (float*)alloc(64);
  float* Gb     = (float*)alloc(16);
  size_t zero_bytes = off;

  float* Smat   = (float*)alloc(4096);
  float* Tmat   = (float*)alloc(4096);
  float* part   = (float*)alloc((size_t)GRID_OUT * 4096);
  float*  inv_norm = (float*)alloc(150016);
  float*  nrm      = (float*)alloc(50016);
  h4*     xnih     = (h4*)alloc((size_t)NI * 32);
  h4*     vuh      = (h4*)alloc((size_t)NU * 32);
  int*    uoff     = (int*)alloc(100016);
  int*    ioff     = (int*)alloc(50016);
  unsigned short* ru_ = (unsigned short*)alloc(500000);
  unsigned short* ri_ = (unsigned short*)alloc(500000);
  int*    uev      = (int*)alloc(1000000);
  unsigned long long* iue = (unsigned long long*)alloc(2000000);
  float*  d_raw    = (float*)alloc(1000000);
  float4* usc      = (float4*)alloc(400000);

  hipMemsetAsync(d_ws, 0, zero_bytes, stream);

  k_norm_count<<<GN_NORM + 1024, 256, 0, stream>>>(x, inv_norm, nrm, xnih, vuh,
                                                   sum_xi, sum_vi,
                                                   u, it, du, di, ru_, ri_, E);
  k_scan2<<<2, 1024, 0, stream>>>(du, NU, uoff, di, NI, ioff);
  k_fused_os<<<GRID_OUT + 4096, 256, 0, stream>>>(x, inv_norm, du, part,
                                                  u, it, ru_, ri_, uoff, ioff, E,
                                                  uev, iue);
  k_redST<<<32, 256, 0, stream>>>(part, Smat, Tmat);
  k_matvec<<<1536, 256, 0, stream>>>(x, inv_norm, Smat, Tmat, out, 1024);
  k_user7<<<2048, 256, 0, stream>>>(x, inv_norm, nrm, xnih, uoff, uev, sum_xi, sum_vi,
                                    d_raw, usc, out, Gx, Gv, Gb);
  k_item7<<<2048, 256, 0, stream>>>(x, inv_norm, vuh, ioff, (const uint2*)iue, d_raw, usc,
                                    Gx, Gv, Gb, out);
}